// Round 13
// baseline (184.900 us; speedup 1.0000x reference)
//
#include <hip/hip_runtime.h>

// ---------------------------------------------------------------------------
// Fused windowed attention (CrossFormer-style SDA).
// B=2, D=256, H=W=256, window 8x8 -> 2048 windows, HEADS=8, DHEAD=32.
// R13: R12 structure + LN stats precomputed by a coalesced stats_kernel
//      (also warms L3 with x) -> attn's LN phase has no barriers/partial sums
//      and its x reads hit L3. LDS 64KB -> 2 blocks/CU.
// ---------------------------------------------------------------------------

typedef __attribute__((ext_vector_type(8))) short bf16x8;
typedef __attribute__((ext_vector_type(4))) short bf16x4;
typedef __attribute__((ext_vector_type(4))) float f32x4;

#define LOG2E    1.44269504088896f
#define QK_SCALE 0.17677669529663687f  // 32^-0.5

__device__ __forceinline__ short f2b(float f) {
  union { float f; unsigned u; } v; v.f = f;
  unsigned r = v.u + 0x7FFFu + ((v.u >> 16) & 1u);  // RNE
  return (short)(r >> 16);
}

__device__ __forceinline__ unsigned pk2(float a, float b) {
  union { float f; unsigned u; } ua, ub; ua.f = a; ub.f = b;
#if __has_builtin(__builtin_amdgcn_perm)
  return __builtin_amdgcn_perm(ub.u + 0x8000u, ua.u + 0x8000u, 0x07060302u);
#else
  return ((ua.u + 0x8000u) >> 16) | ((ub.u + 0x8000u) & 0xFFFF0000u);
#endif
}

__device__ __forceinline__ bf16x8 mk8(unsigned a, unsigned b, unsigned c, unsigned d) {
  union { unsigned u[4]; bf16x8 v; } x; x.u[0] = a; x.u[1] = b; x.u[2] = c; x.u[3] = d;
  return x.v;
}
__device__ __forceinline__ bf16x4 mk4(unsigned a, unsigned b) {
  union { unsigned u[2]; bf16x4 v; } x; x.u[0] = a; x.u[1] = b; return x.v;
}

__device__ __forceinline__ f32x4 mfma16(bf16x4 a, bf16x4 b, f32x4 c) {
#if __has_builtin(__builtin_amdgcn_mfma_f32_16x16x16bf16_1k)
  return __builtin_amdgcn_mfma_f32_16x16x16bf16_1k(a, b, c, 0, 0, 0);
#else
  f32x4 d;
  asm volatile("v_mfma_f32_16x16x16_bf16 %0, %1, %2, %3"
               : "=&v"(d) : "v"(a), "v"(b), "v"(c));
  return d;
#endif
}

__device__ __forceinline__ float wave_sum64(float v) {
  v += __shfl_xor(v, 1);  v += __shfl_xor(v, 2);  v += __shfl_xor(v, 4);
  v += __shfl_xor(v, 8);  v += __shfl_xor(v, 16); v += __shfl_xor(v, 32);
  return v;
}

// ---------------------------------------------------------------------------
// Stats kernel: per-pixel channel mean/rstd via fully coalesced reads
// (256B/wave runs). Also warms L3 with all of x (134MB < 256MB L3).
// statsb[pix] = mean, statsb[131072+pix] = rstd.
// ---------------------------------------------------------------------------
__global__ __launch_bounds__(256)
void stats_kernel(const float* __restrict__ x, float* __restrict__ statsb) {
  const int j = threadIdx.x;
  const int h = blockIdx.x & 255;
  const int b = blockIdx.x >> 8;
  const float* xp = x + ((size_t)b << 24) + (h << 8) + j;
  float s1 = 0.f, s2 = 0.f;
  #pragma unroll 16
  for (int d = 0; d < 256; ++d) {
    float v = xp[(size_t)d << 16];
    s1 += v; s2 += v * v;
  }
  float mean = s1 * (1.f / 256.f);
  float var = s2 * (1.f / 256.f) - mean * mean;   // biased, matches jnp.var
  int pix = (b << 16) + (h << 8) + j;
  statsb[pix] = mean;
  statsb[131072 + pix] = rsqrtf(var + 1e-5f);
}

// ---------------------------------------------------------------------------
// Merged prep: blocks 0..127 convert weights; blocks 128..416 run the DPB MLP.
// ---------------------------------------------------------------------------
__global__ __launch_bounds__(256)
void prep_kernel(const float* __restrict__ wqkv, const float* __restrict__ wout,
                 const float* __restrict__ w1, const float* __restrict__ b1,
                 const float* __restrict__ g1, const float* __restrict__ be1,
                 const float* __restrict__ w2, const float* __restrict__ b2,
                 const float* __restrict__ g2, const float* __restrict__ be2,
                 const float* __restrict__ w3, const float* __restrict__ b3,
                 const float* __restrict__ g3, const float* __restrict__ be3,
                 const float* __restrict__ w4, const float* __restrict__ b4,
                 short* __restrict__ wq_t, short* __restrict__ wo_t,
                 float* __restrict__ sb) {
  __shared__ float h[64];
  __shared__ float wbuf[4096];

  if (blockIdx.x < 128) {
    int t = (blockIdx.x * 256 + threadIdx.x) * 8;
    if (t < 196608) {
      int blk = t >> 9, l = (t & 511) >> 3;
      int et = blk >> 3, kt = blk & 7;
      int e = et * 16 + (l & 15);
      int d = kt * 32 + (l >> 4) * 8;
      const float* src = wqkv + e * 256 + d;
      float sc = (e < 256) ? QK_SCALE * LOG2E : 1.0f;
      bf16x8 pk;
      #pragma unroll
      for (int el = 0; el < 8; ++el) pk[el] = f2b(src[el] * sc);
      *(bf16x8*)(wq_t + t) = pk;
    } else {
      int o = t - 196608;
      int blk = o >> 9, l = (o & 511) >> 3;
      int dt = blk >> 3, kt = blk & 7;
      int dout = dt * 16 + (l & 15);
      int e = kt * 32 + (l >> 4) * 8;
      const float* src = wout + dout * 256 + e;
      bf16x8 pk;
      #pragma unroll
      for (int el = 0; el < 8; ++el) pk[el] = f2b(src[el]);
      *(bf16x8*)(wo_t + o) = pk;
    }
    return;
  }

  if (threadIdx.x >= 64) return;
  const int f = threadIdx.x;
  const int pos = blockIdx.x - 128;   // 0..288
  const float py = (float)(pos / 17) - 8.0f;
  const float px = (float)(pos % 17) - 8.0f;

  float a = py * w1[2 * f] + px * w1[2 * f + 1] + b1[f];
  {
    float m = wave_sum64(a) * (1.f / 64.f);
    float d = a - m;
    float var = wave_sum64(d * d) * (1.f / 64.f);
    a = fmaxf(d * rsqrtf(var + 1e-5f) * g1[f] + be1[f], 0.f);
  }
  h[f] = a;
  __threadfence_block();

  #pragma unroll 8
  for (int k = 0; k < 64; ++k) wbuf[k * 64 + f] = w2[k * 64 + f];
  __threadfence_block();
  float acc = b2[f];
  #pragma unroll 8
  for (int k = 0; k < 64; ++k) {
    int g = (k + f) & 63;
    acc += wbuf[f * 64 + g] * h[g];
  }
  {
    float m = wave_sum64(acc) * (1.f / 64.f);
    float d = acc - m;
    float var = wave_sum64(d * d) * (1.f / 64.f);
    acc = fmaxf(d * rsqrtf(var + 1e-5f) * g2[f] + be2[f], 0.f);
  }
  __threadfence_block();
  h[f] = acc;
  __threadfence_block();

  #pragma unroll 8
  for (int k = 0; k < 64; ++k) wbuf[k * 64 + f] = w3[k * 64 + f];
  __threadfence_block();
  float acc3 = b3[f];
  #pragma unroll 8
  for (int k = 0; k < 64; ++k) {
    int g = (k + f) & 63;
    acc3 += wbuf[f * 64 + g] * h[g];
  }
  {
    float m = wave_sum64(acc3) * (1.f / 64.f);
    float d = acc3 - m;
    float var = wave_sum64(d * d) * (1.f / 64.f);
    acc3 = fmaxf(d * rsqrtf(var + 1e-5f) * g3[f] + be3[f], 0.f);
  }
  float o = wave_sum64(w4[f] * acc3);
  if (f == 0) sb[pos] = o + b4[0];
}

// ---------------------------------------------------------------------------
// Prep C: bias table in fragment order (xLOG2E).
// ---------------------------------------------------------------------------
__global__ __launch_bounds__(512)
void expand_kernel(const float* __restrict__ sb, float* __restrict__ tblf) {
  int idx = blockIdx.x * 512 + threadIdx.x;   // 8 blocks -> 4096
  int it = idx >> 10, jt = (idx >> 8) & 3, ln = (idx >> 2) & 63, jj = idx & 3;
  int rr = ln & 15, gg = ln >> 4;
  int i = it * 16 + rr;
  int j = jt * 16 + gg * 4 + jj;
  int dy = (i >> 3) - (j >> 3) + 7;
  int dx = (i & 7) - (j & 7) + 7;
  tblf[idx] = sb[dy * 15 + dx] * LOG2E;
}

// ---------------------------------------------------------------------------
// Main fused kernel. Block = 2 windows (8 rows x 16 cols). LDS = 64KB:
//   XA2 [128 pos][256 ch] bf16, XASWZ; p2 = row*16 + col16.
//   xn before QKV; overwritten in place by ao after PV.
// ---------------------------------------------------------------------------
#define SM_XA   0
#define SM_SIZE 65536
#define XASWZ(p) ((((p) & 7) << 4) ^ ((((p) >> 3) & 3) << 7))

__global__ __launch_bounds__(512)
void attn_kernel(const float* __restrict__ x, const float* __restrict__ statsb,
                 const short* __restrict__ wq_t, const short* __restrict__ wo_t,
                 const float* __restrict__ gnorm, const float* __restrict__ bnorm,
                 const float* __restrict__ bout, const float* __restrict__ tblf,
                 float* __restrict__ out) {
  __shared__ __align__(16) char smem[SM_SIZE];
  const int t = threadIdx.x;
  const int lane = t & 63;
  const int w = t >> 6;          // wave 0..7 == head
  const int r = lane & 15;
  const int gq = lane >> 4;

  const int bid = blockIdx.x;    // 1024 blocks
  const int b   = bid >> 9;
  const int wh  = (bid >> 4) & 31;
  const int ww2 = bid & 15;
  const int R = wh * 8, C = ww2 * 16;

  // ---- LN with precomputed stats: no barriers, no partial sums ----
  const int n = lane;
  const int d0 = w * 32;
  #pragma unroll
  for (int h = 0; h < 2; ++h) {
    const int row = R + 4 * h + (n >> 4);
    const int col = C + (n & 15);
    const float* xb = x + (((size_t)(b * 256 + d0)) << 16) + row * 256 + col;
    float xv[32];
    #pragma unroll
    for (int i = 0; i < 32; ++i) xv[i] = xb[(size_t)i << 16];
    int pix = (b << 16) + row * 256 + col;
    float mean = statsb[pix];
    float rstd = statsb[131072 + pix];
    int p2 = (4 * h + (n >> 4)) * 16 + (n & 15);
    #pragma unroll
    for (int c = 0; c < 4; ++c) {
      float xn[8];
      #pragma unroll
      for (int e = 0; e < 8; ++e) {
        int d = d0 + c * 8 + e;
        xn[e] = (xv[c * 8 + e] - mean) * rstd * gnorm[d] + bnorm[d];
      }
      *(bf16x8*)(smem + SM_XA + (p2 << 9) + ((((d0 + c * 8) << 1)) ^ XASWZ(p2))) =
          mk8(pk2(xn[0], xn[1]), pk2(xn[2], xn[3]), pk2(xn[4], xn[5]), pk2(xn[6], xn[7]));
    }
  }
  __syncthreads();   // xn complete

  const f32x4 vzero = {0.f, 0.f, 0.f, 0.f};

  // ---- both windows back-to-back; one barrier after ----
  f32x4 o2[2][2][4];
  float pinv[2][4];
  #pragma unroll
  for (int wl = 0; wl < 2; ++wl) {
    // ---- FUSED q+k pass (shared afr): swapped operands -> C[dh][pos] ----
    bf16x4 kpk[2][4], qpk[2][4];
    {
      f32x4 aq[2][4], ak[2][4];
      #pragma unroll
      for (int nt = 0; nt < 2; ++nt)
        #pragma unroll
        for (int t4 = 0; t4 < 4; ++t4) { aq[nt][t4] = vzero; ak[nt][t4] = vzero; }
      #pragma unroll
      for (int kt = 0; kt < 8; ++kt) {
        bf16x8 bq0 = *(const bf16x8*)(wq_t + ((((0 * 16 + w * 2 + 0) * 8 + kt) << 9) + lane * 8));
        bf16x8 bq1 = *(const bf16x8*)(wq_t + ((((0 * 16 + w * 2 + 1) * 8 + kt) << 9) + lane * 8));
        bf16x8 bk0 = *(const bf16x8*)(wq_t + ((((1 * 16 + w * 2 + 0) * 8 + kt) << 9) + lane * 8));
        bf16x8 bk1 = *(const bf16x8*)(wq_t + ((((1 * 16 + w * 2 + 1) * 8 + kt) << 9) + lane * 8));
        bf16x8 afr[4];
        #pragma unroll
        for (int t4 = 0; t4 < 4; ++t4) {
          int p2 = (t4 * 2 + (r >> 3)) * 16 + wl * 8 + (r & 7);
          afr[t4] = *(const bf16x8*)(smem + SM_XA + (p2 << 9) + ((((kt * 32 + gq * 8) << 1)) ^ XASWZ(p2)));
        }
        #pragma unroll
        for (int t4 = 0; t4 < 4; ++t4) {
          aq[0][t4] = __builtin_amdgcn_mfma_f32_16x16x32_bf16(bq0, afr[t4], aq[0][t4], 0, 0, 0);
          aq[1][t4] = __builtin_amdgcn_mfma_f32_16x16x32_bf16(bq1, afr[t4], aq[1][t4], 0, 0, 0);
          ak[0][t4] = __builtin_amdgcn_mfma_f32_16x16x32_bf16(bk0, afr[t4], ak[0][t4], 0, 0, 0);
          ak[1][t4] = __builtin_amdgcn_mfma_f32_16x16x32_bf16(bk1, afr[t4], ak[1][t4], 0, 0, 0);
        }
      }
      #pragma unroll
      for (int kb = 0; kb < 2; ++kb)
        #pragma unroll
        for (int t4 = 0; t4 < 4; ++t4) {
          qpk[kb][t4] = mk4(pk2(aq[kb][t4][0], aq[kb][t4][1]),
                            pk2(aq[kb][t4][2], aq[kb][t4][3]));
          kpk[kb][t4] = mk4(pk2(ak[kb][t4][0], ak[kb][t4][1]),
                            pk2(ak[kb][t4][2], ak[kb][t4][3]));
        }
    }
    // ---- v-pass (ORIGINAL order) -> va8[mt][nt] = PV A-frag (V^T tile) ----
    bf16x4 va8[4][2];
    {
      f32x4 vacc[4][2];
      #pragma unroll
      for (int mt = 0; mt < 4; ++mt)
        #pragma unroll
        for (int nt = 0; nt < 2; ++nt) vacc[mt][nt] = vzero;
      #pragma unroll
      for (int kt = 0; kt < 8; ++kt) {
        bf16x8 bfr0 = *(const bf16x8*)(wq_t + ((((2 * 16 + w * 2 + 0) * 8 + kt) << 9) + lane * 8));
        bf16x8 bfr1 = *(const bf16x8*)(wq_t + ((((2 * 16 + w * 2 + 1) * 8 + kt) << 9) + lane * 8));
        bf16x8 afr[4];
        #pragma unroll
        for (int mt = 0; mt < 4; ++mt) {
          int p2 = (mt * 2 + (r >> 3)) * 16 + wl * 8 + (r & 7);
          afr[mt] = *(const bf16x8*)(smem + SM_XA + (p2 << 9) + ((((kt * 32 + gq * 8) << 1)) ^ XASWZ(p2)));
        }
        #pragma unroll
        for (int mt = 0; mt < 4; ++mt) {
          vacc[mt][0] = __builtin_amdgcn_mfma_f32_16x16x32_bf16(afr[mt], bfr0, vacc[mt][0], 0, 0, 0);
          vacc[mt][1] = __builtin_amdgcn_mfma_f32_16x16x32_bf16(afr[mt], bfr1, vacc[mt][1], 0, 0, 0);
        }
      }
      #pragma unroll
      for (int mt = 0; mt < 4; ++mt)
        #pragma unroll
        for (int nt = 0; nt < 2; ++nt)
          va8[mt][nt] = mk4(pk2(vacc[mt][nt][0], vacc[mt][nt][1]),
                            pk2(vacc[mt][nt][2], vacc[mt][nt][3]));
    }

    // ---- per it-slice: sim + bias + softmax (no max-sub; scores ~ +-5),
    //      P packed UNNORMALIZED; 1/sum folded into ao-write ----
    #pragma unroll
    for (int nt = 0; nt < 2; ++nt)
      #pragma unroll
      for (int it = 0; it < 4; ++it) o2[wl][nt][it] = vzero;
    __builtin_amdgcn_s_setprio(1);
    #pragma unroll
    for (int it = 0; it < 4; ++it) {
      f32x4 sc[4];   // lane holds S[key=jt*16+gq*4+jj][qpos=it*16+r]
      #pragma unroll
      for (int jt = 0; jt < 4; ++jt) {
        sc[jt] = mfma16(kpk[0][jt], qpk[0][it], vzero);
        sc[jt] = mfma16(kpk[1][jt], qpk[1][it], sc[jt]);
      }
      float sum = 0.f;
      #pragma unroll
      for (int jt = 0; jt < 4; ++jt) {
        f32x4 bj = *(const f32x4*)(tblf + (((it * 4 + jt) * 64 + lane) << 2));
        #pragma unroll
        for (int jj = 0; jj < 4; ++jj) {
          float e = exp2f(sc[jt][jj] + bj[jj]);
          sc[jt][jj] = e; sum += e;
        }
      }
      sum += __shfl_xor(sum, 16);
      sum += __shfl_xor(sum, 32);
      pinv[wl][it] = 1.0f / sum;
      bf16x4 ppk[4];   // B-frag: P^T (unnormalized)
      #pragma unroll
      for (int jt = 0; jt < 4; ++jt)
        ppk[jt] = mk4(pk2(sc[jt][0], sc[jt][1]), pk2(sc[jt][2], sc[jt][3]));
      #pragma unroll
      for (int mt = 0; mt < 4; ++mt)
        #pragma unroll
        for (int nt = 0; nt < 2; ++nt)
          o2[wl][nt][it] = mfma16(va8[mt][nt], ppk[mt], o2[wl][nt][it]);
    }
    __builtin_amdgcn_s_setprio(0);
  }
  __syncthreads();   // ALL waves' xn reads (both windows) complete

  // ---- ao into XA (overwrites xn), normalized by pinv here ----
  // o2: lane = O[qpos=it*16+r][dh=nt*16+gq*4+jj]
  #pragma unroll
  for (int wl = 0; wl < 2; ++wl)
    #pragma unroll
    for (int nt = 0; nt < 2; ++nt)
      #pragma unroll
      for (int it = 0; it < 4; ++it) {
        float pv = pinv[wl][it];
        int pw = it * 16 + r;
        int p2 = ((pw >> 3) << 4) + (wl << 3) + (pw & 7);
        int e = (w << 5) + (nt << 4) + (gq << 2);
        *(bf16x4*)(smem + SM_XA + (p2 << 9) + (((e << 1)) ^ XASWZ(p2))) =
            mk4(pk2(o2[wl][nt][it][0] * pv, o2[wl][nt][it][1] * pv),
                pk2(o2[wl][nt][it][2] * pv, o2[wl][nt][it][3] * pv));
      }
  __syncthreads();   // all ao ready

  // ---- out-proj: C[p][dout] = ao . wo^T; woB hoisted, ck serialized ----
  float bov[2];
  bov[0] = bout[w * 32 + r];
  bov[1] = bout[w * 32 + 16 + r];
  bf16x8 woB[2][8];
  #pragma unroll
  for (int nt = 0; nt < 2; ++nt)
    #pragma unroll
    for (int kt = 0; kt < 8; ++kt)
      woB[nt][kt] = *(const bf16x8*)(wo_t + ((((w * 2 + nt) * 8 + kt) << 9) + lane * 8));

  #pragma unroll 1
  for (int ck = 0; ck < 2; ++ck) {
    f32x4 c3[4][2];
    #pragma unroll
    for (int mt = 0; mt < 4; ++mt)
      #pragma unroll
      for (int nt = 0; nt < 2; ++nt) c3[mt][nt] = vzero;
    __builtin_amdgcn_s_setprio(1);
    #pragma unroll
    for (int kt = 0; kt < 8; ++kt) {
      bf16x8 af[4];
      #pragma unroll
      for (int mt = 0; mt < 4; ++mt) {
        int p2 = ck * 64 + mt * 16 + r;
        af[mt] = *(const bf16x8*)(smem + SM_XA + (p2 << 9) + ((((kt * 32 + gq * 8) << 1)) ^ XASWZ(p2)));
      }
      #pragma unroll
      for (int mt = 0; mt < 4; ++mt)
        #pragma unroll
        for (int nt = 0; nt < 2; ++nt)
          c3[mt][nt] = __builtin_amdgcn_mfma_f32_16x16x32_bf16(af[mt], woB[nt][kt], c3[mt][nt], 0, 0, 0);
    }
    __builtin_amdgcn_s_setprio(0);
    // C layout: pos p128 = ck*64 + mt*16 + gq*4 + jj -> row = ck*4+mt,
    // col16 = gq*4+jj; dout = w*32 + nt*16 + r.
    #pragma unroll
    for (int mt = 0; mt < 4; ++mt)
      #pragma unroll
      for (int nt = 0; nt < 2; ++nt) {
        int dout = w * 32 + nt * 16 + r;
        int row = ck * 4 + mt;
        f32x4 v = c3[mt][nt];
        v[0] += bov[nt]; v[1] += bov[nt]; v[2] += bov[nt]; v[3] += bov[nt];
        *(f32x4*)(out + (((size_t)(b * 256 + dout)) << 16) + (R + row) * 256 + C + gq * 4) = v;
      }
  }
}

// ---------------------------------------------------------------------------
extern "C" void kernel_launch(void* const* d_in, const int* in_sizes, int n_in,
                              void* d_out, int out_size, void* d_ws, size_t ws_size,
                              hipStream_t stream) {
  const float* x     = (const float*)d_in[0];
  const float* gnorm = (const float*)d_in[1];
  const float* bnorm = (const float*)d_in[2];
  const float* wqkv  = (const float*)d_in[3];
  const float* wout  = (const float*)d_in[4];
  const float* bout  = (const float*)d_in[5];
  const float* w1  = (const float*)d_in[6];
  const float* b1  = (const float*)d_in[7];
  const float* g1  = (const float*)d_in[8];
  const float* be1 = (const float*)d_in[9];
  const float* w2  = (const float*)d_in[10];
  const float* b2  = (const float*)d_in[11];
  const float* g2  = (const float*)d_in[12];
  const float* be2 = (const float*)d_in[13];
  const float* w3  = (const float*)d_in[14];
  const float* b3  = (const float*)d_in[15];
  const float* g3  = (const float*)d_in[16];
  const float* be3 = (const float*)d_in[17];
  const float* w4  = (const float*)d_in[18];
  const float* b4  = (const float*)d_in[19];

  short* wq_t   = (short*)d_ws;                          // 393216 B
  short* wo_t   = wq_t + 196608;                         // 131072 B
  float* sb     = (float*)((char*)d_ws + 524288);        // 1156 B
  float* tblf   = (float*)((char*)d_ws + 528384);        // 16384 B
  float* statsb = (float*)((char*)d_ws + 544768);        // 1 MB

  stats_kernel<<<dim3(512), dim3(256), 0, stream>>>(x, statsb);
  prep_kernel<<<dim3(417), dim3(256), 0, stream>>>(
      wqkv, wout, w1, b1, g1, be1, w2, b2, g2, be2, w3, b3, g3, be3, w4, b4,
      wq_t, wo_t, sb);
  expand_kernel<<<dim3(8), dim3(512), 0, stream>>>(sb, tblf);

  attn_kernel<<<dim3(1024), dim3(512), 0, stream>>>(
      x, statsb, wq_t, wo_t, gnorm, bnorm, bout, tblf, (float*)d_out);
}

// Round 14
// 166.669 us; speedup vs baseline: 1.1094x; 1.1094x over previous
//
#include <hip/hip_runtime.h>

// ---------------------------------------------------------------------------
// Fused windowed attention (CrossFormer-style SDA).
// B=2, D=256, H=W=256, window 8x8 -> 2048 windows, HEADS=8, DHEAD=32.
// R14: exact R12 structure (best: 177.7us) + setprio on QKV MFMA loops +
//      out-proj weight/bias loads hoisted before the ao-write barrier so
//      their L2 latency hides under LDS writes. 64KB+8KB LDS, 2 blocks/CU.
// ---------------------------------------------------------------------------

typedef __attribute__((ext_vector_type(8))) short bf16x8;
typedef __attribute__((ext_vector_type(4))) short bf16x4;
typedef __attribute__((ext_vector_type(4))) float f32x4;

#define LOG2E    1.44269504088896f
#define QK_SCALE 0.17677669529663687f  // 32^-0.5

__device__ __forceinline__ short f2b(float f) {
  union { float f; unsigned u; } v; v.f = f;
  unsigned r = v.u + 0x7FFFu + ((v.u >> 16) & 1u);  // RNE
  return (short)(r >> 16);
}

__device__ __forceinline__ unsigned pk2(float a, float b) {
  union { float f; unsigned u; } ua, ub; ua.f = a; ub.f = b;
#if __has_builtin(__builtin_amdgcn_perm)
  return __builtin_amdgcn_perm(ub.u + 0x8000u, ua.u + 0x8000u, 0x07060302u);
#else
  return ((ua.u + 0x8000u) >> 16) | ((ub.u + 0x8000u) & 0xFFFF0000u);
#endif
}

__device__ __forceinline__ bf16x8 mk8(unsigned a, unsigned b, unsigned c, unsigned d) {
  union { unsigned u[4]; bf16x8 v; } x; x.u[0] = a; x.u[1] = b; x.u[2] = c; x.u[3] = d;
  return x.v;
}
__device__ __forceinline__ bf16x4 mk4(unsigned a, unsigned b) {
  union { unsigned u[2]; bf16x4 v; } x; x.u[0] = a; x.u[1] = b; return x.v;
}

__device__ __forceinline__ f32x4 mfma16(bf16x4 a, bf16x4 b, f32x4 c) {
#if __has_builtin(__builtin_amdgcn_mfma_f32_16x16x16bf16_1k)
  return __builtin_amdgcn_mfma_f32_16x16x16bf16_1k(a, b, c, 0, 0, 0);
#else
  f32x4 d;
  asm volatile("v_mfma_f32_16x16x16_bf16 %0, %1, %2, %3"
               : "=&v"(d) : "v"(a), "v"(b), "v"(c));
  return d;
#endif
}

__device__ __forceinline__ float wave_sum64(float v) {
  v += __shfl_xor(v, 1);  v += __shfl_xor(v, 2);  v += __shfl_xor(v, 4);
  v += __shfl_xor(v, 8);  v += __shfl_xor(v, 16); v += __shfl_xor(v, 32);
  return v;
}

// ---------------------------------------------------------------------------
// Merged prep: blocks 0..127 convert weights; blocks 128..416 run the DPB MLP.
// ---------------------------------------------------------------------------
__global__ __launch_bounds__(256)
void prep_kernel(const float* __restrict__ wqkv, const float* __restrict__ wout,
                 const float* __restrict__ w1, const float* __restrict__ b1,
                 const float* __restrict__ g1, const float* __restrict__ be1,
                 const float* __restrict__ w2, const float* __restrict__ b2,
                 const float* __restrict__ g2, const float* __restrict__ be2,
                 const float* __restrict__ w3, const float* __restrict__ b3,
                 const float* __restrict__ g3, const float* __restrict__ be3,
                 const float* __restrict__ w4, const float* __restrict__ b4,
                 short* __restrict__ wq_t, short* __restrict__ wo_t,
                 float* __restrict__ sb) {
  __shared__ float h[64];
  __shared__ float wbuf[4096];

  if (blockIdx.x < 128) {
    int t = (blockIdx.x * 256 + threadIdx.x) * 8;
    if (t < 196608) {
      int blk = t >> 9, l = (t & 511) >> 3;
      int et = blk >> 3, kt = blk & 7;
      int e = et * 16 + (l & 15);
      int d = kt * 32 + (l >> 4) * 8;
      const float* src = wqkv + e * 256 + d;
      float sc = (e < 256) ? QK_SCALE * LOG2E : 1.0f;
      bf16x8 pk;
      #pragma unroll
      for (int el = 0; el < 8; ++el) pk[el] = f2b(src[el] * sc);
      *(bf16x8*)(wq_t + t) = pk;
    } else {
      int o = t - 196608;
      int blk = o >> 9, l = (o & 511) >> 3;
      int dt = blk >> 3, kt = blk & 7;
      int dout = dt * 16 + (l & 15);
      int e = kt * 32 + (l >> 4) * 8;
      const float* src = wout + dout * 256 + e;
      bf16x8 pk;
      #pragma unroll
      for (int el = 0; el < 8; ++el) pk[el] = f2b(src[el]);
      *(bf16x8*)(wo_t + o) = pk;
    }
    return;
  }

  if (threadIdx.x >= 64) return;
  const int f = threadIdx.x;
  const int pos = blockIdx.x - 128;   // 0..288
  const float py = (float)(pos / 17) - 8.0f;
  const float px = (float)(pos % 17) - 8.0f;

  float a = py * w1[2 * f] + px * w1[2 * f + 1] + b1[f];
  {
    float m = wave_sum64(a) * (1.f / 64.f);
    float d = a - m;
    float var = wave_sum64(d * d) * (1.f / 64.f);
    a = fmaxf(d * rsqrtf(var + 1e-5f) * g1[f] + be1[f], 0.f);
  }
  h[f] = a;
  __threadfence_block();

  #pragma unroll 8
  for (int k = 0; k < 64; ++k) wbuf[k * 64 + f] = w2[k * 64 + f];
  __threadfence_block();
  float acc = b2[f];
  #pragma unroll 8
  for (int k = 0; k < 64; ++k) {
    int g = (k + f) & 63;
    acc += wbuf[f * 64 + g] * h[g];
  }
  {
    float m = wave_sum64(acc) * (1.f / 64.f);
    float d = acc - m;
    float var = wave_sum64(d * d) * (1.f / 64.f);
    acc = fmaxf(d * rsqrtf(var + 1e-5f) * g2[f] + be2[f], 0.f);
  }
  __threadfence_block();
  h[f] = acc;
  __threadfence_block();

  #pragma unroll 8
  for (int k = 0; k < 64; ++k) wbuf[k * 64 + f] = w3[k * 64 + f];
  __threadfence_block();
  float acc3 = b3[f];
  #pragma unroll 8
  for (int k = 0; k < 64; ++k) {
    int g = (k + f) & 63;
    acc3 += wbuf[f * 64 + g] * h[g];
  }
  {
    float m = wave_sum64(acc3) * (1.f / 64.f);
    float d = acc3 - m;
    float var = wave_sum64(d * d) * (1.f / 64.f);
    acc3 = fmaxf(d * rsqrtf(var + 1e-5f) * g3[f] + be3[f], 0.f);
  }
  float o = wave_sum64(w4[f] * acc3);
  if (f == 0) sb[pos] = o + b4[0];
}

// ---------------------------------------------------------------------------
// Prep C: bias table in fragment order (xLOG2E).
// ---------------------------------------------------------------------------
__global__ __launch_bounds__(512)
void expand_kernel(const float* __restrict__ sb, float* __restrict__ tblf) {
  int idx = blockIdx.x * 512 + threadIdx.x;   // 8 blocks -> 4096
  int it = idx >> 10, jt = (idx >> 8) & 3, ln = (idx >> 2) & 63, jj = idx & 3;
  int rr = ln & 15, gg = ln >> 4;
  int i = it * 16 + rr;
  int j = jt * 16 + gg * 4 + jj;
  int dy = (i >> 3) - (j >> 3) + 7;
  int dx = (i & 7) - (j & 7) + 7;
  tblf[idx] = sb[dy * 15 + dx] * LOG2E;
}

// ---------------------------------------------------------------------------
// Main fused kernel. Block = 2 windows (8 rows x 16 cols). LDS (73728 B):
//   [0    ,65536) XA2 [128 pos][256 ch] bf16, XASWZ; p2 = row*16 + col16.
//   [65536,73728) LN partial sums.
// ---------------------------------------------------------------------------
#define SM_XA   0
#define SM_PS   65536
#define SM_SIZE 73728
#define XASWZ(p) ((((p) & 7) << 4) ^ ((((p) >> 3) & 3) << 7))

__global__ __launch_bounds__(512)
void attn_kernel(const float* __restrict__ x, const float* __restrict__ gnorm,
                 const float* __restrict__ bnorm, const short* __restrict__ wq_t,
                 const short* __restrict__ wo_t, const float* __restrict__ bout,
                 const float* __restrict__ tblf, float* __restrict__ out) {
  __shared__ __align__(16) char smem[SM_SIZE];
  const int t = threadIdx.x;
  const int lane = t & 63;
  const int w = t >> 6;          // wave 0..7 == head
  const int r = lane & 15;
  const int gq = lane >> 4;

  const int bid = blockIdx.x;    // 1024 blocks
  const int b   = bid >> 9;
  const int wh  = (bid >> 4) & 31;
  const int ww2 = bid & 15;
  const int R = wh * 8, C = ww2 * 16;

  // ---- channel-first LayerNorm: both 4-row batches in flight, 1 barrier ----
  const int n = lane;
  const int d0 = w * 32;
  float* PS = (float*)(smem + SM_PS);   // [2][1024] f32
  float xv[2][32];
  #pragma unroll
  for (int h = 0; h < 2; ++h) {
    const float* xb = x + (((size_t)(b * 256 + d0)) << 16) +
                      (R + 4 * h + (n >> 4)) * 256 + C + (n & 15);
    float s1 = 0.f, s2v = 0.f;
    #pragma unroll
    for (int i = 0; i < 32; ++i) {
      float v = xb[(size_t)i << 16];
      xv[h][i] = v; s1 += v; s2v += v * v;
    }
    PS[h * 1024 + w * 64 + n] = s1;
    PS[h * 1024 + 512 + w * 64 + n] = s2v;
  }
  __syncthreads();
  #pragma unroll
  for (int h = 0; h < 2; ++h) {
    float a = 0.f, q2 = 0.f;
    #pragma unroll
    for (int dg = 0; dg < 8; ++dg) {
      a  += PS[h * 1024 + dg * 64 + n];
      q2 += PS[h * 1024 + 512 + dg * 64 + n];
    }
    float mean = a * (1.f / 256.f);
    float var = q2 * (1.f / 256.f) - mean * mean;   // biased, matches jnp.var
    float rstd = rsqrtf(var + 1e-5f);
    int p2 = (4 * h + (n >> 4)) * 16 + (n & 15);
    #pragma unroll
    for (int c = 0; c < 4; ++c) {
      float xn[8];
      #pragma unroll
      for (int e = 0; e < 8; ++e) {
        int d = d0 + c * 8 + e;
        xn[e] = (xv[h][c * 8 + e] - mean) * rstd * gnorm[d] + bnorm[d];
      }
      *(bf16x8*)(smem + SM_XA + (p2 << 9) + ((((d0 + c * 8) << 1)) ^ XASWZ(p2))) =
          mk8(pk2(xn[0], xn[1]), pk2(xn[2], xn[3]), pk2(xn[4], xn[5]), pk2(xn[6], xn[7]));
    }
  }
  __syncthreads();   // xn complete

  const f32x4 vzero = {0.f, 0.f, 0.f, 0.f};

  // ---- both windows back-to-back; one barrier after ----
  f32x4 o2[2][2][4];
  float pinv[2][4];
  #pragma unroll
  for (int wl = 0; wl < 2; ++wl) {
    // ---- FUSED q+k pass (shared afr): swapped operands -> C[dh][pos] ----
    bf16x4 kpk[2][4], qpk[2][4];
    {
      f32x4 aq[2][4], ak[2][4];
      #pragma unroll
      for (int nt = 0; nt < 2; ++nt)
        #pragma unroll
        for (int t4 = 0; t4 < 4; ++t4) { aq[nt][t4] = vzero; ak[nt][t4] = vzero; }
      __builtin_amdgcn_s_setprio(1);
      #pragma unroll
      for (int kt = 0; kt < 8; ++kt) {
        bf16x8 bq0 = *(const bf16x8*)(wq_t + ((((0 * 16 + w * 2 + 0) * 8 + kt) << 9) + lane * 8));
        bf16x8 bq1 = *(const bf16x8*)(wq_t + ((((0 * 16 + w * 2 + 1) * 8 + kt) << 9) + lane * 8));
        bf16x8 bk0 = *(const bf16x8*)(wq_t + ((((1 * 16 + w * 2 + 0) * 8 + kt) << 9) + lane * 8));
        bf16x8 bk1 = *(const bf16x8*)(wq_t + ((((1 * 16 + w * 2 + 1) * 8 + kt) << 9) + lane * 8));
        bf16x8 afr[4];
        #pragma unroll
        for (int t4 = 0; t4 < 4; ++t4) {
          int p2 = (t4 * 2 + (r >> 3)) * 16 + wl * 8 + (r & 7);
          afr[t4] = *(const bf16x8*)(smem + SM_XA + (p2 << 9) + ((((kt * 32 + gq * 8) << 1)) ^ XASWZ(p2)));
        }
        #pragma unroll
        for (int t4 = 0; t4 < 4; ++t4) {
          aq[0][t4] = __builtin_amdgcn_mfma_f32_16x16x32_bf16(bq0, afr[t4], aq[0][t4], 0, 0, 0);
          aq[1][t4] = __builtin_amdgcn_mfma_f32_16x16x32_bf16(bq1, afr[t4], aq[1][t4], 0, 0, 0);
          ak[0][t4] = __builtin_amdgcn_mfma_f32_16x16x32_bf16(bk0, afr[t4], ak[0][t4], 0, 0, 0);
          ak[1][t4] = __builtin_amdgcn_mfma_f32_16x16x32_bf16(bk1, afr[t4], ak[1][t4], 0, 0, 0);
        }
      }
      __builtin_amdgcn_s_setprio(0);
      #pragma unroll
      for (int kb = 0; kb < 2; ++kb)
        #pragma unroll
        for (int t4 = 0; t4 < 4; ++t4) {
          qpk[kb][t4] = mk4(pk2(aq[kb][t4][0], aq[kb][t4][1]),
                            pk2(aq[kb][t4][2], aq[kb][t4][3]));
          kpk[kb][t4] = mk4(pk2(ak[kb][t4][0], ak[kb][t4][1]),
                            pk2(ak[kb][t4][2], ak[kb][t4][3]));
        }
    }
    // ---- v-pass (ORIGINAL order) -> va8[mt][nt] = PV A-frag (V^T tile) ----
    bf16x4 va8[4][2];
    {
      f32x4 vacc[4][2];
      #pragma unroll
      for (int mt = 0; mt < 4; ++mt)
        #pragma unroll
        for (int nt = 0; nt < 2; ++nt) vacc[mt][nt] = vzero;
      __builtin_amdgcn_s_setprio(1);
      #pragma unroll
      for (int kt = 0; kt < 8; ++kt) {
        bf16x8 bfr0 = *(const bf16x8*)(wq_t + ((((2 * 16 + w * 2 + 0) * 8 + kt) << 9) + lane * 8));
        bf16x8 bfr1 = *(const bf16x8*)(wq_t + ((((2 * 16 + w * 2 + 1) * 8 + kt) << 9) + lane * 8));
        bf16x8 afr[4];
        #pragma unroll
        for (int mt = 0; mt < 4; ++mt) {
          int p2 = (mt * 2 + (r >> 3)) * 16 + wl * 8 + (r & 7);
          afr[mt] = *(const bf16x8*)(smem + SM_XA + (p2 << 9) + ((((kt * 32 + gq * 8) << 1)) ^ XASWZ(p2)));
        }
        #pragma unroll
        for (int mt = 0; mt < 4; ++mt) {
          vacc[mt][0] = __builtin_amdgcn_mfma_f32_16x16x32_bf16(afr[mt], bfr0, vacc[mt][0], 0, 0, 0);
          vacc[mt][1] = __builtin_amdgcn_mfma_f32_16x16x32_bf16(afr[mt], bfr1, vacc[mt][1], 0, 0, 0);
        }
      }
      __builtin_amdgcn_s_setprio(0);
      #pragma unroll
      for (int mt = 0; mt < 4; ++mt)
        #pragma unroll
        for (int nt = 0; nt < 2; ++nt)
          va8[mt][nt] = mk4(pk2(vacc[mt][nt][0], vacc[mt][nt][1]),
                            pk2(vacc[mt][nt][2], vacc[mt][nt][3]));
    }

    // ---- per it-slice: sim + bias + softmax (no max-sub; scores ~ +-5),
    //      P packed UNNORMALIZED; 1/sum folded into ao-write ----
    #pragma unroll
    for (int nt = 0; nt < 2; ++nt)
      #pragma unroll
      for (int it = 0; it < 4; ++it) o2[wl][nt][it] = vzero;
    __builtin_amdgcn_s_setprio(1);
    #pragma unroll
    for (int it = 0; it < 4; ++it) {
      f32x4 sc[4];   // lane holds S[key=jt*16+gq*4+jj][qpos=it*16+r]
      #pragma unroll
      for (int jt = 0; jt < 4; ++jt) {
        sc[jt] = mfma16(kpk[0][jt], qpk[0][it], vzero);
        sc[jt] = mfma16(kpk[1][jt], qpk[1][it], sc[jt]);
      }
      float sum = 0.f;
      #pragma unroll
      for (int jt = 0; jt < 4; ++jt) {
        f32x4 bj = *(const f32x4*)(tblf + (((it * 4 + jt) * 64 + lane) << 2));
        #pragma unroll
        for (int jj = 0; jj < 4; ++jj) {
          float e = exp2f(sc[jt][jj] + bj[jj]);
          sc[jt][jj] = e; sum += e;
        }
      }
      sum += __shfl_xor(sum, 16);
      sum += __shfl_xor(sum, 32);
      pinv[wl][it] = 1.0f / sum;
      bf16x4 ppk[4];   // B-frag: P^T (unnormalized)
      #pragma unroll
      for (int jt = 0; jt < 4; ++jt)
        ppk[jt] = mk4(pk2(sc[jt][0], sc[jt][1]), pk2(sc[jt][2], sc[jt][3]));
      #pragma unroll
      for (int mt = 0; mt < 4; ++mt)
        #pragma unroll
        for (int nt = 0; nt < 2; ++nt)
          o2[wl][nt][it] = mfma16(va8[mt][nt], ppk[mt], o2[wl][nt][it]);
    }
    __builtin_amdgcn_s_setprio(0);
  }
  __syncthreads();   // ALL waves' xn reads (both windows) complete

  // ---- hoist out-proj weight/bias loads: latency hides under ao-writes ----
  float bov[2];
  bov[0] = bout[w * 32 + r];
  bov[1] = bout[w * 32 + 16 + r];
  bf16x8 woB[2][8];
  #pragma unroll
  for (int nt = 0; nt < 2; ++nt)
    #pragma unroll
    for (int kt = 0; kt < 8; ++kt)
      woB[nt][kt] = *(const bf16x8*)(wo_t + ((((w * 2 + nt) * 8 + kt) << 9) + lane * 8));

  // ---- ao into XA (overwrites xn), normalized by pinv here ----
  // o2: lane = O[qpos=it*16+r][dh=nt*16+gq*4+jj]
  #pragma unroll
  for (int wl = 0; wl < 2; ++wl)
    #pragma unroll
    for (int nt = 0; nt < 2; ++nt)
      #pragma unroll
      for (int it = 0; it < 4; ++it) {
        float pv = pinv[wl][it];
        int pw = it * 16 + r;
        int p2 = ((pw >> 3) << 4) + (wl << 3) + (pw & 7);
        int e = (w << 5) + (nt << 4) + (gq << 2);
        *(bf16x4*)(smem + SM_XA + (p2 << 9) + (((e << 1)) ^ XASWZ(p2))) =
            mk4(pk2(o2[wl][nt][it][0] * pv, o2[wl][nt][it][1] * pv),
                pk2(o2[wl][nt][it][2] * pv, o2[wl][nt][it][3] * pv));
      }
  __syncthreads();   // all ao ready

  // ---- out-proj: C[p][dout] = ao . wo^T; woB preloaded, ck serialized ----
  #pragma unroll 1
  for (int ck = 0; ck < 2; ++ck) {
    f32x4 c3[4][2];
    #pragma unroll
    for (int mt = 0; mt < 4; ++mt)
      #pragma unroll
      for (int nt = 0; nt < 2; ++nt) c3[mt][nt] = vzero;
    __builtin_amdgcn_s_setprio(1);
    #pragma unroll
    for (int kt = 0; kt < 8; ++kt) {
      bf16x8 af[4];
      #pragma unroll
      for (int mt = 0; mt < 4; ++mt) {
        int p2 = ck * 64 + mt * 16 + r;
        af[mt] = *(const bf16x8*)(smem + SM_XA + (p2 << 9) + ((((kt * 32 + gq * 8) << 1)) ^ XASWZ(p2)));
      }
      #pragma unroll
      for (int mt = 0; mt < 4; ++mt)
        #pragma unroll
        for (int nt = 0; nt < 2; ++nt)
          c3[mt][nt] = __builtin_amdgcn_mfma_f32_16x16x32_bf16(af[mt], woB[nt][kt], c3[mt][nt], 0, 0, 0);
    }
    __builtin_amdgcn_s_setprio(0);
    // C layout: pos p128 = ck*64 + mt*16 + gq*4 + jj -> row = ck*4+mt,
    // col16 = gq*4+jj; dout = w*32 + nt*16 + r.
    #pragma unroll
    for (int mt = 0; mt < 4; ++mt)
      #pragma unroll
      for (int nt = 0; nt < 2; ++nt) {
        int dout = w * 32 + nt * 16 + r;
        int row = ck * 4 + mt;
        f32x4 v = c3[mt][nt];
        v[0] += bov[nt]; v[1] += bov[nt]; v[2] += bov[nt]; v[3] += bov[nt];
        *(f32x4*)(out + (((size_t)(b * 256 + dout)) << 16) + (R + row) * 256 + C + gq * 4) = v;
      }
  }
}

// ---------------------------------------------------------------------------
extern "C" void kernel_launch(void* const* d_in, const int* in_sizes, int n_in,
                              void* d_out, int out_size, void* d_ws, size_t ws_size,
                              hipStream_t stream) {
  const float* x     = (const float*)d_in[0];
  const float* gnorm = (const float*)d_in[1];
  const float* bnorm = (const float*)d_in[2];
  const float* wqkv  = (const float*)d_in[3];
  const float* wout  = (const float*)d_in[4];
  const float* bout  = (const float*)d_in[5];
  const float* w1  = (const float*)d_in[6];
  const float* b1  = (const float*)d_in[7];
  const float* g1  = (const float*)d_in[8];
  const float* be1 = (const float*)d_in[9];
  const float* w2  = (const float*)d_in[10];
  const float* b2  = (const float*)d_in[11];
  const float* g2  = (const float*)d_in[12];
  const float* be2 = (const float*)d_in[13];
  const float* w3  = (const float*)d_in[14];
  const float* b3  = (const float*)d_in[15];
  const float* g3  = (const float*)d_in[16];
  const float* be3 = (const float*)d_in[17];
  const float* w4  = (const float*)d_in[18];
  const float* b4  = (const float*)d_in[19];

  short* wq_t = (short*)d_ws;                           // 393216 B
  short* wo_t = wq_t + 196608;                          // 131072 B
  float* sb   = (float*)((char*)d_ws + 524288);         // 1156 B
  float* tblf = (float*)((char*)d_ws + 528384);         // 16384 B

  prep_kernel<<<dim3(417), dim3(256), 0, stream>>>(
      wqkv, wout, w1, b1, g1, be1, w2, b2, g2, be2, w3, b3, g3, be3, w4, b4,
      wq_t, wo_t, sb);
  expand_kernel<<<dim3(8), dim3(512), 0, stream>>>(sb, tblf);

  attn_kernel<<<dim3(1024), dim3(512), 0, stream>>>(
      x, gnorm, bnorm, wq_t, wo_t, bout, tblf, (float*)d_out);
}